// Round 1
// baseline (432.814 us; speedup 1.0000x reference)
//
#include <hip/hip_runtime.h>

// Problem constants (from reference setup_inputs)
#define TAU    64     // current quantiles
#define TAUP   64     // target quantiles
#define TSTEPS 3
#define BATCH  4096
#define NACT   256
#define GAMMA_F 0.99f

// Kernel 1: one wave (64 threads) per sample b.
// Lane i gathers q[i,b,a], next_n_q[i,b,na], rq[i,b]; LDS-shares q_s_a and rq;
// lane j computes sum_i quantile_huber(target_j, q_i, rq_i); wave-reduce -> td[b].
__global__ __launch_bounds__(64) void iqn_td_kernel(
    const float* __restrict__ q,            // (TAU, BATCH, NACT)
    const float* __restrict__ next_n_q,     // (TAUP, BATCH, NACT)
    const int*   __restrict__ action,       // (BATCH,)
    const int*   __restrict__ next_action,  // (BATCH,)
    const float* __restrict__ reward,       // (TSTEPS, BATCH)
    const int*   __restrict__ done,         // (BATCH,) bool as int32
    const float* __restrict__ rq,           // (TAU, BATCH)
    float*       __restrict__ td_out)       // (BATCH,)
{
    const int b   = blockIdx.x;
    const int tid = threadIdx.x;   // 0..63, = quantile index i and j

    __shared__ float s_q[TAU];
    __shared__ float s_rq[TAU];

    const int a  = action[b];
    const int na = next_action[b];

    // n-step discounted reward (T=3), fp32 to match np reference
    const float g1 = GAMMA_F;
    const float g2 = GAMMA_F * GAMMA_F;
    const float g3 = GAMMA_F * GAMMA_F * GAMMA_F;
    const float r_sum = reward[b] + g1 * reward[BATCH + b] + g2 * reward[2 * BATCH + b];
    const float nd = (done[b] != 0) ? 0.0f : 1.0f;

    // gathers: one independent load per lane (distinct cache lines)
    const size_t plane = (size_t)BATCH * NACT;
    const float qsa  = q[(size_t)tid * plane + (size_t)b * NACT + (size_t)a];
    const float tgtq = next_n_q[(size_t)tid * plane + (size_t)b * NACT + (size_t)na];
    s_q[tid]  = qsa;
    s_rq[tid] = rq[(size_t)tid * BATCH + b];
    __syncthreads();

    // this lane's target quantile value (j = tid)
    const float target = r_sum + g3 * nd * tgtq;

    float acc = 0.0f;
    #pragma unroll
    for (int i = 0; i < TAU; ++i) {
        const float u  = target - s_q[i];
        const float au = fabsf(u);
        const float huber = (au <= 1.0f) ? (0.5f * u * u) : (au - 0.5f);
        const float ind = (u < 0.0f) ? 1.0f : 0.0f;
        acc += fabsf(s_rq[i] - ind) * huber;   // kappa == 1
    }

    // wave-64 reduction over j
    #pragma unroll
    for (int off = 32; off > 0; off >>= 1)
        acc += __shfl_down(acc, off, 64);

    if (tid == 0) td_out[b] = acc * (1.0f / TAUP);
}

// Kernel 2: deterministic weighted mean of td over batch -> loss (d_out[0]).
__global__ __launch_bounds__(256) void iqn_loss_kernel(
    const float* __restrict__ td,      // (BATCH,)
    const float* __restrict__ weight,  // (BATCH,)
    float*       __restrict__ loss)    // (1,)
{
    __shared__ float s_part[4];
    const int tid = threadIdx.x;

    float local = 0.0f;
    for (int i = tid; i < BATCH; i += 256)
        local += td[i] * weight[i];

    #pragma unroll
    for (int off = 32; off > 0; off >>= 1)
        local += __shfl_down(local, off, 64);

    const int wave = tid >> 6;
    if ((tid & 63) == 0) s_part[wave] = local;
    __syncthreads();

    if (tid == 0) {
        const float total = s_part[0] + s_part[1] + s_part[2] + s_part[3];
        loss[0] = total * (1.0f / BATCH);
    }
}

extern "C" void kernel_launch(void* const* d_in, const int* in_sizes, int n_in,
                              void* d_out, int out_size, void* d_ws, size_t ws_size,
                              hipStream_t stream) {
    const float* q           = (const float*)d_in[0];
    const float* next_n_q    = (const float*)d_in[1];
    const int*   action      = (const int*)d_in[2];
    const int*   next_action = (const int*)d_in[3];
    const float* reward      = (const float*)d_in[4];
    const int*   done        = (const int*)d_in[5];
    const float* rq          = (const float*)d_in[6];
    const float* weight      = (const float*)d_in[7];

    float* out = (float*)d_out;          // out[0] = loss, out[1..4096] = td per sample
    float* td  = out + 1;

    iqn_td_kernel<<<BATCH, 64, 0, stream>>>(q, next_n_q, action, next_action,
                                            reward, done, rq, td);
    iqn_loss_kernel<<<1, 256, 0, stream>>>(td, weight, out);
}

// Round 2
// 428.301 us; speedup vs baseline: 1.0105x; 1.0105x over previous
//
#include <hip/hip_runtime.h>

// Problem constants (from reference setup_inputs)
#define TAU    64     // current quantiles
#define TAUP   64     // target quantiles
#define BATCH  4096
#define NACT   256
#define GAMMA_F 0.99f

// One wave (64 lanes) handles 2 samples; block = 256 threads = 4 waves = 8 samples.
// Lane i gathers q[i,b,a], next_n_q[i,b,na], rq[i,b] for both samples (6 independent
// gathers in flight). Broadcast via __shfl (no LDS, no barrier). Each lane j computes
// its target-quantile row-sum; butterfly reduce; lane 0 stores td[b] and accumulates
// the weighted loss contribution into LDS; thread 0 does one atomicAdd per block.
__global__ __launch_bounds__(256) void iqn_td_fused_kernel(
    const float* __restrict__ q,            // (TAU, BATCH, NACT)
    const float* __restrict__ next_n_q,     // (TAUP, BATCH, NACT)
    const int*   __restrict__ action,       // (BATCH,)
    const int*   __restrict__ next_action,  // (BATCH,)
    const float* __restrict__ reward,       // (3, BATCH)
    const int*   __restrict__ done,         // (BATCH,)
    const float* __restrict__ rq,           // (TAU, BATCH)
    const float* __restrict__ weight,       // (BATCH,)
    float*       __restrict__ loss,         // (1,)  pre-zeroed via memset
    float*       __restrict__ td_out)       // (BATCH,)
{
    const int tid  = threadIdx.x;
    const int wave = tid >> 6;
    const int lane = tid & 63;
    const int b0   = blockIdx.x * 8 + wave * 2;   // this wave's two samples
    const int b1   = b0 + 1;

    __shared__ float s_part[4];

    // index loads first so gathers can issue ASAP
    const int a0  = action[b0];
    const int a1  = action[b1];
    const int na0 = next_action[b0];
    const int na1 = next_action[b1];

    // 6 independent big gathers (distinct cache lines each)
    const size_t plane = (size_t)BATCH * NACT;
    const size_t lrow  = (size_t)lane * plane;
    const float qsa0 = q[lrow + (size_t)b0 * NACT + (size_t)a0];
    const float qsa1 = q[lrow + (size_t)b1 * NACT + (size_t)a1];
    const float tg0  = next_n_q[lrow + (size_t)b0 * NACT + (size_t)na0];
    const float tg1  = next_n_q[lrow + (size_t)b1 * NACT + (size_t)na1];
    const float rq0  = rq[(size_t)lane * BATCH + b0];
    const float rq1  = rq[(size_t)lane * BATCH + b1];

    // small per-sample scalars
    const float g1 = GAMMA_F;
    const float g2 = GAMMA_F * GAMMA_F;
    const float g3 = GAMMA_F * GAMMA_F * GAMMA_F;
    const float rs0 = reward[b0] + g1 * reward[BATCH + b0] + g2 * reward[2 * BATCH + b0];
    const float rs1 = reward[b1] + g1 * reward[BATCH + b1] + g2 * reward[2 * BATCH + b1];
    const float nd0 = (done[b0] != 0) ? 0.0f : 1.0f;
    const float nd1 = (done[b1] != 0) ? 0.0f : 1.0f;

    // this lane's target quantile value (j = lane)
    const float target0 = rs0 + g3 * nd0 * tg0;
    const float target1 = rs1 + g3 * nd1 * tg1;

    float acc0 = 0.0f, acc1 = 0.0f;
    #pragma unroll
    for (int i = 0; i < TAU; ++i) {
        const float qi0  = __shfl(qsa0, i, 64);
        const float qi1  = __shfl(qsa1, i, 64);
        const float rqi0 = __shfl(rq0, i, 64);
        const float rqi1 = __shfl(rq1, i, 64);

        const float u0  = target0 - qi0;
        const float au0 = fabsf(u0);
        const float h0  = (au0 <= 1.0f) ? (0.5f * u0 * u0) : (au0 - 0.5f);
        const float in0 = (u0 < 0.0f) ? 1.0f : 0.0f;
        acc0 += fabsf(rqi0 - in0) * h0;

        const float u1  = target1 - qi1;
        const float au1 = fabsf(u1);
        const float h1  = (au1 <= 1.0f) ? (0.5f * u1 * u1) : (au1 - 0.5f);
        const float in1 = (u1 < 0.0f) ? 1.0f : 0.0f;
        acc1 += fabsf(rqi1 - in1) * h1;
    }

    // wave-64 butterfly reduction over j for both samples
    #pragma unroll
    for (int off = 32; off > 0; off >>= 1) {
        acc0 += __shfl_down(acc0, off, 64);
        acc1 += __shfl_down(acc1, off, 64);
    }

    if (lane == 0) {
        const float td0 = acc0 * (1.0f / TAUP);
        const float td1 = acc1 * (1.0f / TAUP);
        td_out[b0] = td0;
        td_out[b1] = td1;
        s_part[wave] = (td0 * weight[b0] + td1 * weight[b1]) * (1.0f / BATCH);
    }
    __syncthreads();

    if (tid == 0) {
        atomicAdd(loss, s_part[0] + s_part[1] + s_part[2] + s_part[3]);
    }
}

extern "C" void kernel_launch(void* const* d_in, const int* in_sizes, int n_in,
                              void* d_out, int out_size, void* d_ws, size_t ws_size,
                              hipStream_t stream) {
    const float* q           = (const float*)d_in[0];
    const float* next_n_q    = (const float*)d_in[1];
    const int*   action      = (const int*)d_in[2];
    const int*   next_action = (const int*)d_in[3];
    const float* reward      = (const float*)d_in[4];
    const int*   done        = (const int*)d_in[5];
    const float* rq          = (const float*)d_in[6];
    const float* weight      = (const float*)d_in[7];

    float* out = (float*)d_out;   // out[0] = loss, out[1..4096] = td per sample
    float* td  = out + 1;

    // zero the loss accumulator (d_out is poisoned 0xAA before every launch)
    hipMemsetAsync(out, 0, sizeof(float), stream);

    // 4096 samples / 8 per block = 512 blocks
    iqn_td_fused_kernel<<<BATCH / 8, 256, 0, stream>>>(
        q, next_n_q, action, next_action, reward, done, rq, weight, out, td);
}